// Round 2
// baseline (779.767 us; speedup 1.0000x reference)
//
#include <hip/hip_runtime.h>

typedef unsigned short ushort_t;
typedef __attribute__((ext_vector_type(4))) unsigned short ushort4_t;
typedef __attribute__((ext_vector_type(8))) unsigned short ushort8;
typedef __attribute__((ext_vector_type(8))) __bf16 bf16x8;
typedef __attribute__((ext_vector_type(4))) float f32x4;

typedef const unsigned int __attribute__((address_space(1)))* gas_ptr;
typedef unsigned int __attribute__((address_space(3)))* las_ptr;

__device__ __forceinline__ float b2f(unsigned short u) {
    union { unsigned int i; float f; } x; x.i = ((unsigned int)u) << 16; return x.f;
}
__device__ __forceinline__ unsigned short f2b(float f) {
    union { float f; unsigned int i; } x; x.f = f;
    unsigned int r = (x.i + 0x7fffu + ((x.i >> 16) & 1u)) >> 16;  // RNE
    return (unsigned short)r;
}

// ---------------- fp32 -> bf16 convert (weights) ----------------
__global__ __launch_bounds__(256) void cvt_kernel(const float* __restrict__ x,
        ushort_t* __restrict__ y) {
    size_t i = (size_t)blockIdx.x * 256 + threadIdx.x;
    f32x4 v = *(const f32x4*)(x + i * 4);
    ushort4_t o;
    #pragma unroll
    for (int t = 0; t < 4; ++t) o[t] = f2b(v[t]);
    *(ushort4_t*)(y + i * 4) = o;
}

// ---------------- LayerNorm: one wave per 1024-elem row, fp32 in -> bf16 out ----------------
__global__ __launch_bounds__(256) void ln_kernel(const float* __restrict__ x,
        const float* __restrict__ gamma, const float* __restrict__ beta,
        ushort_t* __restrict__ y) {
    int wave = threadIdx.x >> 6, lane = threadIdx.x & 63;
    size_t row = (size_t)blockIdx.x * 4 + wave;
    const float* xr = x + row * 1024;
    f32x4 v[4];
    #pragma unroll
    for (int c = 0; c < 4; ++c) v[c] = *(const f32x4*)(xr + c * 256 + lane * 4);
    float s = 0.f, s2 = 0.f;
    #pragma unroll
    for (int c = 0; c < 4; ++c)
        #pragma unroll
        for (int t = 0; t < 4; ++t) { s += v[c][t]; s2 += v[c][t] * v[c][t]; }
    #pragma unroll
    for (int off = 1; off < 64; off <<= 1) {
        s  += __shfl_xor(s,  off, 64);
        s2 += __shfl_xor(s2, off, 64);
    }
    float mean = s * (1.0f / 1024.0f);
    float var  = fmaxf(s2 * (1.0f / 1024.0f) - mean * mean, 0.f);
    float rstd = rsqrtf(var + 1e-5f);
    ushort_t* yr = y + row * 1024;
    #pragma unroll
    for (int c = 0; c < 4; ++c) {
        f32x4 g = *(const f32x4*)(gamma + c * 256 + lane * 4);
        f32x4 b = *(const f32x4*)(beta  + c * 256 + lane * 4);
        ushort4_t o;
        #pragma unroll
        for (int t = 0; t < 4; ++t)
            o[t] = f2b((v[c][t] - mean) * rstd * g[t] + b[t]);
        *(ushort4_t*)(yr + c * 256 + lane * 4) = o;
    }
}

// ---------------- bt-GEMM: C[M,N] = A[M,K] * B[N,K]^T (bf16 in, fp32 acc) ----------------
// m97 structure: 128x128 tile, BK=32, 256 thr (4 waves, 2x2 of 64x64), global_load_lds w=16
template <bool OUT_F32>
__global__ __launch_bounds__(256) void gemm_bt(const ushort_t* __restrict__ A,
        const ushort_t* __restrict__ B, void* __restrict__ Cv,
        int M, int N, int K) {
    __shared__ ushort_t lA[128 * 32];
    __shared__ ushort_t lB[128 * 32];
    const int tid = threadIdx.x;
    const int wave = tid >> 6, lane = tid & 63;
    const int m0 = blockIdx.y * 128, n0 = blockIdx.x * 128;
    const int mb = (wave >> 1) * 64, nb = (wave & 1) * 64;
    const int r = lane & 15, q = lane >> 4;
    const int q8 = q * 8;
    f32x4 acc[4][4];
    #pragma unroll
    for (int i = 0; i < 4; ++i)
        #pragma unroll
        for (int j = 0; j < 4; ++j)
            acc[i][j] = (f32x4){0.f, 0.f, 0.f, 0.f};
    const int li0 = tid, li1 = tid + 256;
    const int rowT0 = li0 >> 2, colT0 = (li0 & 3) * 8;
    const int rowT1 = li1 >> 2, colT1 = (li1 & 3) * 8;
    for (int kt = 0; kt < K; kt += 32) {
        const ushort_t* Ak = A + (size_t)m0 * K + kt;
        const ushort_t* Bk = B + (size_t)n0 * K + kt;
        __builtin_amdgcn_global_load_lds((gas_ptr)(Ak + (size_t)rowT0 * K + colT0), (las_ptr)(lA + li0 * 8), 16, 0, 0);
        __builtin_amdgcn_global_load_lds((gas_ptr)(Ak + (size_t)rowT1 * K + colT1), (las_ptr)(lA + li1 * 8), 16, 0, 0);
        __builtin_amdgcn_global_load_lds((gas_ptr)(Bk + (size_t)rowT0 * K + colT0), (las_ptr)(lB + li0 * 8), 16, 0, 0);
        __builtin_amdgcn_global_load_lds((gas_ptr)(Bk + (size_t)rowT1 * K + colT1), (las_ptr)(lB + li1 * 8), 16, 0, 0);
        __syncthreads();   // drains vmcnt(0) -> LDS tiles visible
        bf16x8 af[4], bfr[4];
        #pragma unroll
        for (int i = 0; i < 4; ++i) af[i]  = *(const bf16x8*)(lA + (mb + i * 16 + r) * 32 + q8);
        #pragma unroll
        for (int j = 0; j < 4; ++j) bfr[j] = *(const bf16x8*)(lB + (nb + j * 16 + r) * 32 + q8);
        #pragma unroll
        for (int i = 0; i < 4; ++i)
            #pragma unroll
            for (int j = 0; j < 4; ++j)
                acc[i][j] = __builtin_amdgcn_mfma_f32_16x16x32_bf16(af[i], bfr[j], acc[i][j], 0, 0, 0);
        __syncthreads();   // compute done before next tile overwrite
    }
    // C/D layout: col = lane&15, row = (lane>>4)*4 + reg
    #pragma unroll
    for (int i = 0; i < 4; ++i) {
        #pragma unroll
        for (int rr = 0; rr < 4; ++rr) {
            int rowC = m0 + mb + i * 16 + q * 4 + rr;
            if (OUT_F32) {
                float* Cr = (float*)Cv + (size_t)rowC * N + n0 + nb + r;
                #pragma unroll
                for (int j = 0; j < 4; ++j)
                    Cr[j * 16] = acc[i][j][rr];
            } else {
                ushort_t* Cr = (ushort_t*)Cv + (size_t)rowC * N + n0 + nb + r;
                #pragma unroll
                for (int j = 0; j < 4; ++j)
                    Cr[j * 16] = f2b(acc[i][j][rr]);
            }
        }
    }
}

// ---------------- per-position 8x8 attention, one wave per position ----------------
// out may alias qin (in-place over query buffer): wave stages its own Q before writing.
__global__ __launch_bounds__(256) void attn_kernel(const ushort_t* qin,
        const ushort_t* kvin, ushort_t* outp) {
    __shared__ ushort_t sm[4 * 3072];
    int wave = threadIdx.x >> 6, lane = threadIdx.x & 63;
    size_t p = (size_t)blockIdx.x * 4 + wave;
    ushort_t* sQ = sm + wave * 3072;
    ushort_t* sKV = sQ + 1024;
    const ushort_t* qp  = qin  + p * 1024;
    const ushort_t* kvp = kvin + p * 2048;
    *(ushort8*)(sQ + lane * 8)       = *(const ushort8*)(qp + lane * 8);
    *(ushort8*)(sQ + 512 + lane * 8) = *(const ushort8*)(qp + 512 + lane * 8);
    #pragma unroll
    for (int s = 0; s < 4; ++s)
        *(ushort8*)(sKV + s * 512 + lane * 8) = *(const ushort8*)(kvp + s * 512 + lane * 8);
    __syncthreads();
    // scores: lane (h = lane>>3, g = lane&7): dot(Q[h,:], K[g,:]) over 128
    int h = lane >> 3;
    int g = lane & 7;
    float sc = 0.f;
    #pragma unroll
    for (int j = 0; j < 128; j += 8) {
        ushort8 a = *(const ushort8*)(sQ + h * 128 + j);
        ushort8 k = *(const ushort8*)(sKV + g * 128 + j);
        #pragma unroll
        for (int t = 0; t < 8; ++t) sc += b2f(a[t]) * b2f(k[t]);
    }
    sc *= 0.08838834764831845f;   // 128^-0.5
    // softmax over g (groups of 8 lanes)
    float mx = sc;
    mx = fmaxf(mx, __shfl_xor(mx, 1, 64));
    mx = fmaxf(mx, __shfl_xor(mx, 2, 64));
    mx = fmaxf(mx, __shfl_xor(mx, 4, 64));
    float e = __expf(sc - mx);
    float den = e;
    den += __shfl_xor(den, 1, 64);
    den += __shfl_xor(den, 2, 64);
    den += __shfl_xor(den, 4, 64);
    float w = e / den;
    // context: lane handles (h = lane>>3, d0 = (lane&7)*16)
    int d0 = (lane & 7) * 16;
    int gb = lane & 56;
    float accv[16];
    #pragma unroll
    for (int t = 0; t < 16; ++t) accv[t] = 0.f;
    #pragma unroll
    for (int gg = 0; gg < 8; ++gg) {
        float wg = __shfl(w, gb + gg, 64);
        const ushort_t* vr = sKV + 1024 + gg * 128 + d0;
        ushort8 x0 = *(const ushort8*)(vr);
        ushort8 x1 = *(const ushort8*)(vr + 8);
        #pragma unroll
        for (int t = 0; t < 8; ++t) {
            accv[t]     += wg * b2f(x0[t]);
            accv[8 + t] += wg * b2f(x1[t]);
        }
    }
    ushort8 o0, o1;
    #pragma unroll
    for (int t = 0; t < 8; ++t) { o0[t] = f2b(accv[t]); o1[t] = f2b(accv[8 + t]); }
    ushort_t* op = outp + p * 1024 + h * 128 + d0;
    *(ushort8*)(op)     = o0;
    *(ushort8*)(op + 8) = o1;
}

extern "C" void kernel_launch(void* const* d_in, const int* in_sizes, int n_in,
                              void* d_out, int out_size, void* d_ws, size_t ws_size,
                              hipStream_t stream) {
    const float* q   = (const float*)d_in[0];
    const float* kv  = (const float*)d_in[1];
    const float* gm  = (const float*)d_in[2];
    const float* bm  = (const float*)d_in[3];
    const float* gl  = (const float*)d_in[4];
    const float* bl  = (const float*)d_in[5];
    const float* Wq  = (const float*)d_in[6];
    const float* Wkv = (const float*)d_in[7];
    const float* Wo  = (const float*)d_in[8];
    float* out = (float*)d_out;

    const int ROWS = 16 * 2048;           // 32768
    ushort_t* ws     = (ushort_t*)d_ws;
    ushort_t* norm   = ws;                                   // 64 MB: kvn, then qn (bf16)
    ushort_t* kvproj = norm + (size_t)ROWS * 1024;           // 128 MB: [ROWS, 2048] bf16
    ushort_t* qbuf   = kvproj + (size_t)ROWS * 2048;         // 64 MB: query, then context (bf16)
    ushort_t* wq_b   = qbuf + (size_t)ROWS * 1024;           // 2 MB
    ushort_t* wkv_b  = wq_b + 1024 * 1024;                   // 4 MB
    ushort_t* wo_b   = wkv_b + 2048 * 1024;                  // 2 MB

    // 0) weights fp32 -> bf16
    cvt_kernel<<<(1024 * 1024) / 1024, 256, 0, stream>>>(Wq,  wq_b);
    cvt_kernel<<<(2048 * 1024) / 1024, 256, 0, stream>>>(Wkv, wkv_b);
    cvt_kernel<<<(1024 * 1024) / 1024, 256, 0, stream>>>(Wo,  wo_b);
    // 1) LN(kv) -> norm
    ln_kernel<<<ROWS / 4, 256, 0, stream>>>(kv, gl, bl, norm);
    // 2) norm @ Wkv^T -> kvproj  [ROWS, 2048]
    gemm_bt<false><<<dim3(2048 / 128, ROWS / 128), 256, 0, stream>>>(norm, wkv_b, kvproj, ROWS, 2048, 1024);
    // 3) LN(q) -> norm (kvn dead)
    ln_kernel<<<ROWS / 4, 256, 0, stream>>>(q, gm, bm, norm);
    // 4) norm @ Wq^T -> qbuf  [ROWS, 1024]
    gemm_bt<false><<<dim3(1024 / 128, ROWS / 128), 256, 0, stream>>>(norm, wq_b, qbuf, ROWS, 1024, 1024);
    // 5) attention per position, context written in place over qbuf
    attn_kernel<<<ROWS / 4, 256, 0, stream>>>(qbuf, kvproj, qbuf);
    // 6) context @ Wo^T -> out (fp32)
    gemm_bt<true><<<dim3(1024 / 128, ROWS / 128), 256, 0, stream>>>(qbuf, wo_b, out, ROWS, 1024, 1024);
}

// Round 3
// 767.583 us; speedup vs baseline: 1.0159x; 1.0159x over previous
//
#include <hip/hip_runtime.h>

typedef unsigned short ushort_t;
typedef __attribute__((ext_vector_type(4))) unsigned short ushort4_t;
typedef __attribute__((ext_vector_type(8))) unsigned short ushort8;
typedef __attribute__((ext_vector_type(8))) __bf16 bf16x8;
typedef __attribute__((ext_vector_type(4))) float f32x4;

typedef const unsigned int __attribute__((address_space(1)))* gas_ptr;
typedef unsigned int __attribute__((address_space(3)))* las_ptr;

__device__ __forceinline__ float b2f(unsigned short u) {
    union { unsigned int i; float f; } x; x.i = ((unsigned int)u) << 16; return x.f;
}
__device__ __forceinline__ unsigned short f2b(float f) {
    union { float f; unsigned int i; } x; x.f = f;
    unsigned int r = (x.i + 0x7fffu + ((x.i >> 16) & 1u)) >> 16;  // RNE
    return (unsigned short)r;
}

// ---------------- fp32 -> bf16 convert, all three weight mats in one launch ----------------
__global__ __launch_bounds__(256) void cvt_kernel(const float* __restrict__ wq,
        const float* __restrict__ wkv, const float* __restrict__ wo,
        ushort_t* __restrict__ yq, ushort_t* __restrict__ ykv, ushort_t* __restrict__ yo) {
    int b = blockIdx.x;
    const float* x; ushort_t* y; size_t off;
    if (b < 1024)      { x = wq;  y = yq;  off = (size_t)b * 1024; }
    else if (b < 3072) { x = wkv; y = ykv; off = (size_t)(b - 1024) * 1024; }
    else               { x = wo;  y = yo;  off = (size_t)(b - 3072) * 1024; }
    size_t i = off + threadIdx.x * 4;
    f32x4 v = *(const f32x4*)(x + i);
    ushort4_t o;
    #pragma unroll
    for (int t = 0; t < 4; ++t) o[t] = f2b(v[t]);
    *(ushort4_t*)(y + i) = o;
}

// ---------------- LayerNorm: one wave per 1024-elem row, fp32 in -> bf16 out ----------------
__global__ __launch_bounds__(256) void ln_kernel(const float* __restrict__ x,
        const float* __restrict__ gamma, const float* __restrict__ beta,
        ushort_t* __restrict__ y) {
    int wave = threadIdx.x >> 6, lane = threadIdx.x & 63;
    size_t row = (size_t)blockIdx.x * 4 + wave;
    const float* xr = x + row * 1024;
    f32x4 v[4];
    #pragma unroll
    for (int c = 0; c < 4; ++c) v[c] = *(const f32x4*)(xr + c * 256 + lane * 4);
    float s = 0.f, s2 = 0.f;
    #pragma unroll
    for (int c = 0; c < 4; ++c)
        #pragma unroll
        for (int t = 0; t < 4; ++t) { s += v[c][t]; s2 += v[c][t] * v[c][t]; }
    #pragma unroll
    for (int off = 1; off < 64; off <<= 1) {
        s  += __shfl_xor(s,  off, 64);
        s2 += __shfl_xor(s2, off, 64);
    }
    float mean = s * (1.0f / 1024.0f);
    float var  = fmaxf(s2 * (1.0f / 1024.0f) - mean * mean, 0.f);
    float rstd = rsqrtf(var + 1e-5f);
    ushort_t* yr = y + row * 1024;
    #pragma unroll
    for (int c = 0; c < 4; ++c) {
        f32x4 g = *(const f32x4*)(gamma + c * 256 + lane * 4);
        f32x4 b = *(const f32x4*)(beta  + c * 256 + lane * 4);
        ushort4_t o;
        #pragma unroll
        for (int t = 0; t < 4; ++t)
            o[t] = f2b((v[c][t] - mean) * rstd * g[t] + b[t]);
        *(ushort4_t*)(yr + c * 256 + lane * 4) = o;
    }
}

// ---------------- bt-GEMM: C[M,N] = A[M,K] * B[N,K]^T (bf16 in, fp32 acc) ----------------
// m97 structure: 128x128 tile, BK=32, 256 thr (4 waves, 2x2 of 64x64), global_load_lds w=16.
// LDS layout is XOR-swizzled at 16B-chunk granularity: chunk (row, c) lives at index
// row*4 + ((c + (row>>1)) & 3). This makes 8 consecutive reader lanes hit 8 distinct
// bank groups (was 2 -> 4..8-way conflict, SQ_LDS_BANK_CONFLICT 1.7e7). Because
// global_load_lds dest is hardwired to base+lane*16, the swizzle is realized by
// permuting which global chunk each lane fetches (same 64B row segment -> still coalesced).
template <bool OUT_F32>
__global__ __launch_bounds__(256) void gemm_bt(const ushort_t* __restrict__ A,
        const ushort_t* __restrict__ B, void* __restrict__ Cv,
        int M, int N, int K) {
    __shared__ ushort_t lA[128 * 32];
    __shared__ ushort_t lB[128 * 32];
    const int tid = threadIdx.x;
    const int wave = tid >> 6, lane = tid & 63;
    const int m0 = blockIdx.y * 128, n0 = blockIdx.x * 128;
    const int mb = (wave >> 1) * 64, nb = (wave & 1) * 64;
    const int r = lane & 15, q = lane >> 4;
    f32x4 acc[4][4];
    #pragma unroll
    for (int i = 0; i < 4; ++i)
        #pragma unroll
        for (int j = 0; j < 4; ++j)
            acc[i][j] = (f32x4){0.f, 0.f, 0.f, 0.f};
    const int li0 = tid, li1 = tid + 256;
    // swizzled source chunk for each staging lane
    const int rowT0 = li0 >> 2, colT0 = (((li0 & 3) - ((li0 >> 3) & 3)) & 3) * 8;
    const int rowT1 = li1 >> 2, colT1 = (((li1 & 3) - ((li1 >> 3) & 3)) & 3) * 8;
    for (int kt = 0; kt < K; kt += 32) {
        const ushort_t* Ak = A + (size_t)m0 * K + kt;
        const ushort_t* Bk = B + (size_t)n0 * K + kt;
        __builtin_amdgcn_global_load_lds((gas_ptr)(Ak + (size_t)rowT0 * K + colT0), (las_ptr)(lA + li0 * 8), 16, 0, 0);
        __builtin_amdgcn_global_load_lds((gas_ptr)(Ak + (size_t)rowT1 * K + colT1), (las_ptr)(lA + li1 * 8), 16, 0, 0);
        __builtin_amdgcn_global_load_lds((gas_ptr)(Bk + (size_t)rowT0 * K + colT0), (las_ptr)(lB + li0 * 8), 16, 0, 0);
        __builtin_amdgcn_global_load_lds((gas_ptr)(Bk + (size_t)rowT1 * K + colT1), (las_ptr)(lB + li1 * 8), 16, 0, 0);
        __syncthreads();   // drains vmcnt(0) -> LDS tiles visible
        bf16x8 af[4], bfr[4];
        #pragma unroll
        for (int i = 0; i < 4; ++i) {
            int row = mb + i * 16 + r;
            af[i]  = *(const bf16x8*)(lA + (row * 4 + ((q + (row >> 1)) & 3)) * 8);
        }
        #pragma unroll
        for (int j = 0; j < 4; ++j) {
            int row = nb + j * 16 + r;
            bfr[j] = *(const bf16x8*)(lB + (row * 4 + ((q + (row >> 1)) & 3)) * 8);
        }
        #pragma unroll
        for (int i = 0; i < 4; ++i)
            #pragma unroll
            for (int j = 0; j < 4; ++j)
                acc[i][j] = __builtin_amdgcn_mfma_f32_16x16x32_bf16(af[i], bfr[j], acc[i][j], 0, 0, 0);
        __syncthreads();   // compute done before next tile overwrite
    }
    // C/D layout: col = lane&15, row = (lane>>4)*4 + reg
    #pragma unroll
    for (int i = 0; i < 4; ++i) {
        #pragma unroll
        for (int rr = 0; rr < 4; ++rr) {
            int rowC = m0 + mb + i * 16 + q * 4 + rr;
            if (OUT_F32) {
                float* Cr = (float*)Cv + (size_t)rowC * N + n0 + nb + r;
                #pragma unroll
                for (int j = 0; j < 4; ++j)
                    Cr[j * 16] = acc[i][j][rr];
            } else {
                ushort_t* Cr = (ushort_t*)Cv + (size_t)rowC * N + n0 + nb + r;
                #pragma unroll
                for (int j = 0; j < 4; ++j)
                    Cr[j * 16] = f2b(acc[i][j][rr]);
            }
        }
    }
}

// ---------------- per-position 8x8 attention, one wave per position ----------------
// out may alias qin (in-place over query buffer): wave stages its own Q before writing.
__global__ __launch_bounds__(256) void attn_kernel(const ushort_t* qin,
        const ushort_t* kvin, ushort_t* outp) {
    __shared__ ushort_t sm[4 * 3072];
    int wave = threadIdx.x >> 6, lane = threadIdx.x & 63;
    size_t p = (size_t)blockIdx.x * 4 + wave;
    ushort_t* sQ = sm + wave * 3072;
    ushort_t* sKV = sQ + 1024;
    const ushort_t* qp  = qin  + p * 1024;
    const ushort_t* kvp = kvin + p * 2048;
    *(ushort8*)(sQ + lane * 8)       = *(const ushort8*)(qp + lane * 8);
    *(ushort8*)(sQ + 512 + lane * 8) = *(const ushort8*)(qp + 512 + lane * 8);
    #pragma unroll
    for (int s = 0; s < 4; ++s)
        *(ushort8*)(sKV + s * 512 + lane * 8) = *(const ushort8*)(kvp + s * 512 + lane * 8);
    __syncthreads();
    // scores: lane (h = lane>>3, g = lane&7): dot(Q[h,:], K[g,:]) over 128
    int h = lane >> 3;
    int g = lane & 7;
    float sc = 0.f;
    #pragma unroll
    for (int j = 0; j < 128; j += 8) {
        ushort8 a = *(const ushort8*)(sQ + h * 128 + j);
        ushort8 k = *(const ushort8*)(sKV + g * 128 + j);
        #pragma unroll
        for (int t = 0; t < 8; ++t) sc += b2f(a[t]) * b2f(k[t]);
    }
    sc *= 0.08838834764831845f;   // 128^-0.5
    // softmax over g (groups of 8 lanes)
    float mx = sc;
    mx = fmaxf(mx, __shfl_xor(mx, 1, 64));
    mx = fmaxf(mx, __shfl_xor(mx, 2, 64));
    mx = fmaxf(mx, __shfl_xor(mx, 4, 64));
    float e = __expf(sc - mx);
    float den = e;
    den += __shfl_xor(den, 1, 64);
    den += __shfl_xor(den, 2, 64);
    den += __shfl_xor(den, 4, 64);
    float w = e / den;
    // context: lane handles (h = lane>>3, d0 = (lane&7)*16)
    int d0 = (lane & 7) * 16;
    int gb = lane & 56;
    float accv[16];
    #pragma unroll
    for (int t = 0; t < 16; ++t) accv[t] = 0.f;
    #pragma unroll
    for (int gg = 0; gg < 8; ++gg) {
        float wg = __shfl(w, gb + gg, 64);
        const ushort_t* vr = sKV + 1024 + gg * 128 + d0;
        ushort8 x0 = *(const ushort8*)(vr);
        ushort8 x1 = *(const ushort8*)(vr + 8);
        #pragma unroll
        for (int t = 0; t < 8; ++t) {
            accv[t]     += wg * b2f(x0[t]);
            accv[8 + t] += wg * b2f(x1[t]);
        }
    }
    ushort8 o0, o1;
    #pragma unroll
    for (int t = 0; t < 8; ++t) { o0[t] = f2b(accv[t]); o1[t] = f2b(accv[8 + t]); }
    ushort_t* op = outp + p * 1024 + h * 128 + d0;
    *(ushort8*)(op)     = o0;
    *(ushort8*)(op + 8) = o1;
}

extern "C" void kernel_launch(void* const* d_in, const int* in_sizes, int n_in,
                              void* d_out, int out_size, void* d_ws, size_t ws_size,
                              hipStream_t stream) {
    const float* q   = (const float*)d_in[0];
    const float* kv  = (const float*)d_in[1];
    const float* gm  = (const float*)d_in[2];
    const float* bm  = (const float*)d_in[3];
    const float* gl  = (const float*)d_in[4];
    const float* bl  = (const float*)d_in[5];
    const float* Wq  = (const float*)d_in[6];
    const float* Wkv = (const float*)d_in[7];
    const float* Wo  = (const float*)d_in[8];
    float* out = (float*)d_out;

    const int ROWS = 16 * 2048;           // 32768
    ushort_t* ws     = (ushort_t*)d_ws;
    ushort_t* norm   = ws;                                   // 64 MB: kvn, then qn (bf16)
    ushort_t* kvproj = norm + (size_t)ROWS * 1024;           // 128 MB: [ROWS, 2048] bf16
    ushort_t* qbuf   = kvproj + (size_t)ROWS * 2048;         // 64 MB: query, then context (bf16)
    ushort_t* wq_b   = qbuf + (size_t)ROWS * 1024;           // 2 MB
    ushort_t* wkv_b  = wq_b + 1024 * 1024;                   // 4 MB
    ushort_t* wo_b   = wkv_b + 2048 * 1024;                  // 2 MB

    // 0) weights fp32 -> bf16 (single launch, 4096 blocks)
    cvt_kernel<<<4096, 256, 0, stream>>>(Wq, Wkv, Wo, wq_b, wkv_b, wo_b);
    // 1) LN(kv) -> norm
    ln_kernel<<<ROWS / 4, 256, 0, stream>>>(kv, gl, bl, norm);
    // 2) norm @ Wkv^T -> kvproj  [ROWS, 2048]
    gemm_bt<false><<<dim3(2048 / 128, ROWS / 128), 256, 0, stream>>>(norm, wkv_b, kvproj, ROWS, 2048, 1024);
    // 3) LN(q) -> norm (kvn dead)
    ln_kernel<<<ROWS / 4, 256, 0, stream>>>(q, gm, bm, norm);
    // 4) norm @ Wq^T -> qbuf  [ROWS, 1024]
    gemm_bt<false><<<dim3(1024 / 128, ROWS / 128), 256, 0, stream>>>(norm, wq_b, qbuf, ROWS, 1024, 1024);
    // 5) attention per position, context written in place over qbuf
    attn_kernel<<<ROWS / 4, 256, 0, stream>>>(qbuf, kvproj, qbuf);
    // 6) context @ Wo^T -> out (fp32)
    gemm_bt<true><<<dim3(1024 / 128, ROWS / 128), 256, 0, stream>>>(qbuf, wo_b, out, ROWS, 1024, 1024);
}